// Round 1
// baseline (644.913 us; speedup 1.0000x reference)
//
#include <hip/hip_runtime.h>
#include <hip/hip_fp16.h>

// Problem constants
#define OUT_F 4096
#define IN_F  4096
#define M_TOTAL 8192          // 4 * 2048
#define TOTAL_W (OUT_F * IN_F)

typedef _Float16 f16x8 __attribute__((ext_vector_type(8)));
typedef float    f32x4 __attribute__((ext_vector_type(4)));

__device__ const float NF4_LUT_C[16] = {
    -1.0f, -0.6961928009986877f, -0.5250730514526367f, -0.39491748809814453f,
    -0.28444138169288635f, -0.18477343022823334f, -0.09105003625154495f, 0.0f,
    0.07958029955625534f, 0.16093020141124725f, 0.24611230194568634f,
    0.33791524171829224f, 0.44070982933044434f, 0.5626170039176941f,
    0.7229568362236023f, 1.0f};

// ---------------- Dequant: indices + q_scales -> W fp16 [OUT_F][IN_F] ----------------
// 8 elements per thread; block scale covers 64 elements so all 8 share one scale.
__global__ __launch_bounds__(256) void k_dequant(const int* __restrict__ idx,
                                                 const int* __restrict__ qs,
                                                 _Float16* __restrict__ W) {
    __shared__ float slut[16];
    if (threadIdx.x < 16) slut[threadIdx.x] = NF4_LUT_C[threadIdx.x];
    __syncthreads();
    int t = blockIdx.x * 256 + threadIdx.x;              // 0 .. TOTAL_W/8-1
    const int4* ip = (const int4*)idx;
    int4 a = ip[2 * t];
    int4 b = ip[2 * t + 1];
    // exact reference order: (q/127)*0.05 in fp32, then vals*absmax, then fp16 cast
    float absmax = ((float)qs[t >> 3] / 127.0f) * 0.05f;
    f16x8 o;
    o[0] = (_Float16)(slut[a.x] * absmax);
    o[1] = (_Float16)(slut[a.y] * absmax);
    o[2] = (_Float16)(slut[a.z] * absmax);
    o[3] = (_Float16)(slut[a.w] * absmax);
    o[4] = (_Float16)(slut[b.x] * absmax);
    o[5] = (_Float16)(slut[b.y] * absmax);
    o[6] = (_Float16)(slut[b.z] * absmax);
    o[7] = (_Float16)(slut[b.w] * absmax);
    *(f16x8*)(W + (size_t)t * 8) = o;
}

// ---------------- Cast X fp32 -> fp16 ----------------
__global__ __launch_bounds__(256) void k_cast(const float* __restrict__ x,
                                              _Float16* __restrict__ xh) {
    int t = blockIdx.x * 256 + threadIdx.x;              // 8 elems per thread
    const float4* xp = (const float4*)x;
    float4 a = xp[2 * t];
    float4 b = xp[2 * t + 1];
    f16x8 o;
    o[0] = (_Float16)a.x; o[1] = (_Float16)a.y; o[2] = (_Float16)a.z; o[3] = (_Float16)a.w;
    o[4] = (_Float16)b.x; o[5] = (_Float16)b.y; o[6] = (_Float16)b.z; o[7] = (_Float16)b.w;
    *(f16x8*)(xh + (size_t)t * 8) = o;
}

// ---------------- GEMM: C[M][N] = A[M][K] * B[N][K]^T  (m97 structure) ----------------
// 128x128 block tile, 4 waves in 2x2, each wave 64x64 via 4x4 grid of 16x16x32 MFMA.
// BK=32. LDS tiles contiguous [128][32] fp16 (no padding: global_load_lds needs
// wave-uniform base + lane*16 contiguity).

__device__ __forceinline__ void async16(const _Float16* g, _Float16* l) {
    __builtin_amdgcn_global_load_lds(
        (const __attribute__((address_space(1))) void*)g,
        (__attribute__((address_space(3))) void*)l,
        16, 0, 0);
}

__global__ __launch_bounds__(256) void k_gemm(const _Float16* __restrict__ A,
                                              const _Float16* __restrict__ B,
                                              float* __restrict__ C) {
    const int K = IN_F, N = OUT_F;
    __shared__ _Float16 sA[128 * 32];
    __shared__ _Float16 sB[128 * 32];

    const int tid  = threadIdx.x;
    const int m0   = blockIdx.y * 128;
    const int n0   = blockIdx.x * 128;
    const int lane = tid & 63;
    const int wave = tid >> 6;
    const int wm   = (wave >> 1) * 64;   // wave M offset inside tile
    const int wn   = (wave & 1) * 64;    // wave N offset inside tile
    const int fr   = lane & 15;          // fragment row (m or n)
    const int quad = lane >> 4;          // k-quad

    f32x4 acc[4][4];
#pragma unroll
    for (int i = 0; i < 4; i++)
#pragma unroll
        for (int j = 0; j < 4; j++) acc[i][j] = (f32x4){0.f, 0.f, 0.f, 0.f};

    // staging decomposition: chunk c = j*256 + tid; row = c>>2; k-sub = (c&3)*8
    const int r0 = tid >> 2, kc0 = (tid & 3) * 8;            // j = 0
    const int r1 = (256 + tid) >> 2, kc1 = kc0;              // j = 1 (c&3 unchanged)
    const _Float16* a0 = A + (size_t)(m0 + r0) * K + kc0;
    const _Float16* a1 = A + (size_t)(m0 + r1) * K + kc1;
    const _Float16* b0 = B + (size_t)(n0 + r0) * K + kc0;
    const _Float16* b1 = B + (size_t)(n0 + r1) * K + kc1;
    _Float16* lA0 = &sA[(size_t)tid * 8];
    _Float16* lA1 = &sA[(size_t)(256 + tid) * 8];
    _Float16* lB0 = &sB[(size_t)tid * 8];
    _Float16* lB1 = &sB[(size_t)(256 + tid) * 8];

    for (int kt = 0; kt < K; kt += 32) {
        async16(a0 + kt, lA0);
        async16(a1 + kt, lA1);
        async16(b0 + kt, lB0);
        async16(b1 + kt, lB1);
        __syncthreads();   // drains vmcnt for global_load_lds

        f16x8 af[4], bf[4];
#pragma unroll
        for (int i = 0; i < 4; i++) {
            af[i] = *(const f16x8*)&sA[(wm + i * 16 + fr) * 32 + quad * 8];
            bf[i] = *(const f16x8*)&sB[(wn + i * 16 + fr) * 32 + quad * 8];
        }
#pragma unroll
        for (int mi = 0; mi < 4; mi++)
#pragma unroll
            for (int ni = 0; ni < 4; ni++)
                acc[mi][ni] = __builtin_amdgcn_mfma_f32_16x16x32_f16(
                    af[mi], bf[ni], acc[mi][ni], 0, 0, 0);
        __syncthreads();   // protect LDS before next overwrite
    }

    // Epilogue: C/D layout col=lane&15, row=quad*4+reg
#pragma unroll
    for (int mi = 0; mi < 4; mi++)
#pragma unroll
        for (int ni = 0; ni < 4; ni++)
#pragma unroll
            for (int r = 0; r < 4; r++) {
                int row = m0 + wm + mi * 16 + quad * 4 + r;
                int col = n0 + wn + ni * 16 + fr;
                C[(size_t)row * N + col] = acc[mi][ni][r];
            }
}

extern "C" void kernel_launch(void* const* d_in, const int* in_sizes, int n_in,
                              void* d_out, int out_size, void* d_ws, size_t ws_size,
                              hipStream_t stream) {
    const float* x       = (const float*)d_in[0];
    const int*   indices = (const int*)d_in[1];
    const int*   qscales = (const int*)d_in[2];
    float*       out     = (float*)d_out;

    _Float16* W  = (_Float16*)d_ws;                                   // 32 MiB
    _Float16* Xh = (_Float16*)((char*)d_ws + (size_t)TOTAL_W * 2);    // 64 MiB

    k_dequant<<<TOTAL_W / 8 / 256, 256, 0, stream>>>(indices, qscales, W);
    k_cast<<<(size_t)M_TOTAL * IN_F / 8 / 256, 256, 0, stream>>>(x, Xh);

    dim3 grid(OUT_F / 128, M_TOTAL / 128);   // (N-tiles=32, M-tiles=64)
    k_gemm<<<grid, 256, 0, stream>>>(Xh, W, out);
}

// Round 2
// 633.541 us; speedup vs baseline: 1.0180x; 1.0180x over previous
//
#include <hip/hip_runtime.h>
#include <hip/hip_fp16.h>

// Problem constants
#define OUT_F 4096
#define IN_F  4096
#define M_TOTAL 8192          // 4 * 2048
#define TOTAL_W (OUT_F * IN_F)

typedef _Float16 f16x8 __attribute__((ext_vector_type(8)));
typedef float    f32x4 __attribute__((ext_vector_type(4)));

__device__ const float NF4_LUT_C[16] = {
    -1.0f, -0.6961928009986877f, -0.5250730514526367f, -0.39491748809814453f,
    -0.28444138169288635f, -0.18477343022823334f, -0.09105003625154495f, 0.0f,
    0.07958029955625534f, 0.16093020141124725f, 0.24611230194568634f,
    0.33791524171829224f, 0.44070982933044434f, 0.5626170039176941f,
    0.7229568362236023f, 1.0f};

// ---------------- Dequant: indices + q_scales -> W fp16 [OUT_F][IN_F] ----------------
__global__ __launch_bounds__(256) void k_dequant(const int* __restrict__ idx,
                                                 const int* __restrict__ qs,
                                                 _Float16* __restrict__ W) {
    __shared__ float slut[16];
    if (threadIdx.x < 16) slut[threadIdx.x] = NF4_LUT_C[threadIdx.x];
    __syncthreads();
    int t = blockIdx.x * 256 + threadIdx.x;              // 0 .. TOTAL_W/8-1
    const int4* ip = (const int4*)idx;
    int4 a = ip[2 * t];
    int4 b = ip[2 * t + 1];
    // exact reference order: (q/127)*0.05 in fp32, then vals*absmax, then fp16 cast
    float absmax = ((float)qs[t >> 3] / 127.0f) * 0.05f;
    f16x8 o;
    o[0] = (_Float16)(slut[a.x] * absmax);
    o[1] = (_Float16)(slut[a.y] * absmax);
    o[2] = (_Float16)(slut[a.z] * absmax);
    o[3] = (_Float16)(slut[a.w] * absmax);
    o[4] = (_Float16)(slut[b.x] * absmax);
    o[5] = (_Float16)(slut[b.y] * absmax);
    o[6] = (_Float16)(slut[b.z] * absmax);
    o[7] = (_Float16)(slut[b.w] * absmax);
    *(f16x8*)(W + (size_t)t * 8) = o;
}

// ---------------- Cast X fp32 -> fp16 ----------------
__global__ __launch_bounds__(256) void k_cast(const float* __restrict__ x,
                                              _Float16* __restrict__ xh) {
    int t = blockIdx.x * 256 + threadIdx.x;              // 8 elems per thread
    const float4* xp = (const float4*)x;
    float4 a = xp[2 * t];
    float4 b = xp[2 * t + 1];
    f16x8 o;
    o[0] = (_Float16)a.x; o[1] = (_Float16)a.y; o[2] = (_Float16)a.z; o[3] = (_Float16)a.w;
    o[4] = (_Float16)b.x; o[5] = (_Float16)b.y; o[6] = (_Float16)b.z; o[7] = (_Float16)b.w;
    *(f16x8*)(xh + (size_t)t * 8) = o;
}

// ---------------- GEMM: C[M][N] = A[M][K] * B[N][K]^T ----------------
// 128x128 tile, 4 waves 2x2, each wave 64x64 via 4x4 of 16x16x32 MFMA, BK=32.
// LDS: 16B chunks, XOR-swizzled: logical (row r, kchunk kc) lives at physical
// chunk p = r*4 + (kc ^ ((r>>1)&3)).  Staging permutes the GLOBAL k-offset
// (LDS dest must stay lane-contiguous for global_load_lds); fragment reads
// then spread each 8-lane LDS service group over all 8 four-bank groups
// (2 lanes/bank = free, vs 8-way conflict unswizzled).

__device__ __forceinline__ void async16(const _Float16* g, _Float16* l) {
    __builtin_amdgcn_global_load_lds(
        (const __attribute__((address_space(1))) void*)g,
        (__attribute__((address_space(3))) void*)l,
        16, 0, 0);
}

__global__ __launch_bounds__(256) void k_gemm(const _Float16* __restrict__ A,
                                              const _Float16* __restrict__ B,
                                              float* __restrict__ C) {
    const int K = IN_F, N = OUT_F;
    __shared__ _Float16 sA[128 * 32];
    __shared__ _Float16 sB[128 * 32];

    const int tid  = threadIdx.x;
    // Super-block raster: 64-block groups = 8 M-tiles x 8 N-tiles for L2 reuse.
    const int bid = blockIdx.x;            // 0..2047
    const int g   = bid >> 6;              // 32 groups
    const int gy  = g >> 2;                // 8 M-supers
    const int gx  = g & 3;                 // 4 N-supers
    const int w   = bid & 63;
    const int m0  = (gy * 8 + (w >> 3)) * 128;
    const int n0  = (gx * 8 + (w & 7)) * 128;

    const int lane = tid & 63;
    const int wave = tid >> 6;
    const int wm   = (wave >> 1) * 64;
    const int wn   = (wave & 1) * 64;
    const int fr   = lane & 15;           // fragment row (m or n)
    const int quad = lane >> 4;           // k-quad

    f32x4 acc[4][4];
#pragma unroll
    for (int i = 0; i < 4; i++)
#pragma unroll
        for (int j = 0; j < 4; j++) acc[i][j] = (f32x4){0.f, 0.f, 0.f, 0.f};

    // Staging: thread tid fills physical chunks tid and 256+tid.
    // Physical chunk p: row = p>>2, global k-chunk = (p&3) ^ ((row>>1)&3).
    const int r0  = tid >> 2;             // row of chunk tid  (0..63)
    const int r1  = 64 + r0;              // row of chunk 256+tid
    const int kc  = (((tid & 3) ^ ((tid >> 3) & 3))) * 8;  // same for both chunks
    const _Float16* a0 = A + (size_t)(m0 + r0) * K + kc;
    const _Float16* a1 = A + (size_t)(m0 + r1) * K + kc;
    const _Float16* b0 = B + (size_t)(n0 + r0) * K + kc;
    const _Float16* b1 = B + (size_t)(n0 + r1) * K + kc;
    _Float16* lA0 = &sA[(size_t)tid * 8];
    _Float16* lA1 = &sA[(size_t)(256 + tid) * 8];
    _Float16* lB0 = &sB[(size_t)tid * 8];
    _Float16* lB1 = &sB[(size_t)(256 + tid) * 8];

    // Read-side swizzle term: r = wm + i*16 + fr, (r>>1)&3 == (fr>>1)&3
    // (wm, i*16 are multiples of 16) -> i-invariant, hoisted out of the loop.
    const int kx = (quad ^ ((fr >> 1) & 3)) * 8;

    for (int kt = 0; kt < K; kt += 32) {
        async16(a0 + kt, lA0);
        async16(a1 + kt, lA1);
        async16(b0 + kt, lB0);
        async16(b1 + kt, lB1);
        __syncthreads();   // drains vmcnt for global_load_lds

        f16x8 af[4], bf[4];
#pragma unroll
        for (int i = 0; i < 4; i++) {
            af[i] = *(const f16x8*)&sA[(wm + i * 16 + fr) * 32 + kx];
            bf[i] = *(const f16x8*)&sB[(wn + i * 16 + fr) * 32 + kx];
        }
#pragma unroll
        for (int mi = 0; mi < 4; mi++)
#pragma unroll
            for (int ni = 0; ni < 4; ni++)
                acc[mi][ni] = __builtin_amdgcn_mfma_f32_16x16x32_f16(
                    af[mi], bf[ni], acc[mi][ni], 0, 0, 0);
        __syncthreads();   // protect LDS before next overwrite
    }

    // Epilogue: C/D layout col=lane&15, row=quad*4+reg
#pragma unroll
    for (int mi = 0; mi < 4; mi++)
#pragma unroll
        for (int ni = 0; ni < 4; ni++)
#pragma unroll
            for (int r = 0; r < 4; r++) {
                int row = m0 + wm + mi * 16 + quad * 4 + r;
                int col = n0 + wn + ni * 16 + fr;
                C[(size_t)row * N + col] = acc[mi][ni][r];
            }
}

extern "C" void kernel_launch(void* const* d_in, const int* in_sizes, int n_in,
                              void* d_out, int out_size, void* d_ws, size_t ws_size,
                              hipStream_t stream) {
    const float* x       = (const float*)d_in[0];
    const int*   indices = (const int*)d_in[1];
    const int*   qscales = (const int*)d_in[2];
    float*       out     = (float*)d_out;

    _Float16* W  = (_Float16*)d_ws;                                   // 32 MiB
    _Float16* Xh = (_Float16*)((char*)d_ws + (size_t)TOTAL_W * 2);    // 64 MiB

    k_dequant<<<TOTAL_W / 8 / 256, 256, 0, stream>>>(indices, qscales, W);
    k_cast<<<(size_t)M_TOTAL * IN_F / 8 / 256, 256, 0, stream>>>(x, Xh);

    k_gemm<<<2048, 256, 0, stream>>>(Xh, W, out);
}

// Round 3
// 566.821 us; speedup vs baseline: 1.1378x; 1.1177x over previous
//
#include <hip/hip_runtime.h>
#include <hip/hip_fp16.h>

// Problem constants
#define OUT_F 4096
#define IN_F  4096
#define M_TOTAL 8192          // 4 * 2048
#define TOTAL_W (OUT_F * IN_F)

typedef _Float16 f16x8 __attribute__((ext_vector_type(8)));
typedef float    f32x16 __attribute__((ext_vector_type(16)));

__device__ const float NF4_LUT_C[16] = {
    -1.0f, -0.6961928009986877f, -0.5250730514526367f, -0.39491748809814453f,
    -0.28444138169288635f, -0.18477343022823334f, -0.09105003625154495f, 0.0f,
    0.07958029955625534f, 0.16093020141124725f, 0.24611230194568634f,
    0.33791524171829224f, 0.44070982933044434f, 0.5626170039176941f,
    0.7229568362236023f, 1.0f};

// ---------------- Dequant: indices + q_scales -> W fp16 [OUT_F][IN_F] ----------------
__global__ __launch_bounds__(256) void k_dequant(const int* __restrict__ idx,
                                                 const int* __restrict__ qs,
                                                 _Float16* __restrict__ W) {
    __shared__ float slut[16];
    if (threadIdx.x < 16) slut[threadIdx.x] = NF4_LUT_C[threadIdx.x];
    __syncthreads();
    int t = blockIdx.x * 256 + threadIdx.x;              // 0 .. TOTAL_W/8-1
    const int4* ip = (const int4*)idx;
    int4 a = ip[2 * t];
    int4 b = ip[2 * t + 1];
    // exact reference order: (q/127)*0.05 in fp32, then vals*absmax, then fp16 cast
    float absmax = ((float)qs[t >> 3] / 127.0f) * 0.05f;
    f16x8 o;
    o[0] = (_Float16)(slut[a.x] * absmax);
    o[1] = (_Float16)(slut[a.y] * absmax);
    o[2] = (_Float16)(slut[a.z] * absmax);
    o[3] = (_Float16)(slut[a.w] * absmax);
    o[4] = (_Float16)(slut[b.x] * absmax);
    o[5] = (_Float16)(slut[b.y] * absmax);
    o[6] = (_Float16)(slut[b.z] * absmax);
    o[7] = (_Float16)(slut[b.w] * absmax);
    *(f16x8*)(W + (size_t)t * 8) = o;
}

// ---------------- Cast X fp32 -> fp16 ----------------
__global__ __launch_bounds__(256) void k_cast(const float* __restrict__ x,
                                              _Float16* __restrict__ xh) {
    int t = blockIdx.x * 256 + threadIdx.x;              // 8 elems per thread
    const float4* xp = (const float4*)x;
    float4 a = xp[2 * t];
    float4 b = xp[2 * t + 1];
    f16x8 o;
    o[0] = (_Float16)a.x; o[1] = (_Float16)a.y; o[2] = (_Float16)a.z; o[3] = (_Float16)a.w;
    o[4] = (_Float16)b.x; o[5] = (_Float16)b.y; o[6] = (_Float16)b.z; o[7] = (_Float16)b.w;
    *(f16x8*)(xh + (size_t)t * 8) = o;
}

// ---------------- GEMM: C[M][N] = A[M][K] * B[N][K]^T ----------------
// 128x128 tile, 4 waves 2x2, each wave 64x64 via 2x2 of 32x32x16 MFMA, BK=64.
// LDS tiles [128][64] fp16 (16 KB each), 16B chunks XOR-swizzled:
//   logical (row r, kchunk kc in 0..7) -> physical chunk r*8 + (kc ^ (r&7)).
// Staging permutes the GLOBAL k-offset (LDS dest stays lane-contiguous for
// global_load_lds). Read side: swizzle term (r&7) == (lane&31)&7, invariant
// across the 32-row mfma sub-tiles -> conflict-free (8 lanes/bank-group over
// an 8-phase b128 service).

__device__ __forceinline__ void async16(const _Float16* g, _Float16* l) {
    __builtin_amdgcn_global_load_lds(
        (const __attribute__((address_space(1))) void*)g,
        (__attribute__((address_space(3))) void*)l,
        16, 0, 0);
}

__global__ __launch_bounds__(256) void k_gemm(const _Float16* __restrict__ A,
                                              const _Float16* __restrict__ B,
                                              float* __restrict__ C) {
    const int K = IN_F, N = OUT_F;
    __shared__ _Float16 sA[128 * 64];
    __shared__ _Float16 sB[128 * 64];

    const int tid  = threadIdx.x;
    // Super-block raster: 64-block groups = 8 M-tiles x 8 N-tiles for L2 reuse.
    const int bid = blockIdx.x;            // 0..2047
    const int g   = bid >> 6;              // 32 groups
    const int gy  = g >> 2;                // 8 M-supers
    const int gx  = g & 3;                 // 4 N-supers
    const int w   = bid & 63;
    const int m0  = (gy * 8 + (w >> 3)) * 128;
    const int n0  = (gx * 8 + (w & 7)) * 128;

    const int lane = tid & 63;
    const int wave = tid >> 6;
    const int wm   = (wave >> 1) * 64;
    const int wn   = (wave & 1) * 64;
    const int m    = lane & 31;           // mfma row/col within 32
    const int h    = lane >> 5;           // k-half selector
    const int sw   = m & 7;               // read-side swizzle term

    f32x16 acc[2][2];
#pragma unroll
    for (int i = 0; i < 2; i++)
#pragma unroll
        for (int j = 0; j < 2; j++)
#pragma unroll
            for (int r = 0; r < 16; r++) acc[i][j][r] = 0.f;

    // Staging: thread t fills physical chunks {j*256+t, j=0..3} per tile.
    // chunk p: row = p>>3 = j*32 + (t>>3), pos = p&7 = t&7,
    // global k-chunk = pos ^ (row&7) = (t&7) ^ ((t>>3)&7)  (j-invariant).
    const int rr  = tid >> 3;                              // 0..31
    const int kc  = ((tid & 7) ^ (rr & 7)) * 8;            // global k elem offset
    const _Float16* ag[4];
    const _Float16* bg[4];
    _Float16* lA[4];
    _Float16* lB[4];
#pragma unroll
    for (int j = 0; j < 4; j++) {
        int row = j * 32 + rr;
        ag[j] = A + (size_t)(m0 + row) * K + kc;
        bg[j] = B + (size_t)(n0 + row) * K + kc;
        lA[j] = &sA[(size_t)(j * 256 + tid) * 8];
        lB[j] = &sB[(size_t)(j * 256 + tid) * 8];
    }

    for (int kt = 0; kt < K; kt += 64) {
#pragma unroll
        for (int j = 0; j < 4; j++) async16(ag[j] + kt, lA[j]);
#pragma unroll
        for (int j = 0; j < 4; j++) async16(bg[j] + kt, lB[j]);
        __syncthreads();   // drains vmcnt for global_load_lds

#pragma unroll
        for (int s = 0; s < 4; s++) {      // 4 k-steps of 16
            const int pos = ((s * 2 + h) ^ sw) * 8;
            f16x8 af[2], bf[2];
#pragma unroll
            for (int i = 0; i < 2; i++) {
                af[i] = *(const f16x8*)&sA[(wm + i * 32 + m) * 64 + pos];
                bf[i] = *(const f16x8*)&sB[(wn + i * 32 + m) * 64 + pos];
            }
#pragma unroll
            for (int mi = 0; mi < 2; mi++)
#pragma unroll
                for (int ni = 0; ni < 2; ni++)
                    acc[mi][ni] = __builtin_amdgcn_mfma_f32_32x32x16_f16(
                        af[mi], bf[ni], acc[mi][ni], 0, 0, 0);
        }
        __syncthreads();   // protect LDS before next overwrite
    }

    // Epilogue: 32x32 C/D layout col=lane&31, row=(reg&3)+8*(reg>>2)+4*(lane>>5)
#pragma unroll
    for (int mi = 0; mi < 2; mi++)
#pragma unroll
        for (int ni = 0; ni < 2; ni++)
#pragma unroll
            for (int r = 0; r < 16; r++) {
                int row = m0 + wm + mi * 32 + (r & 3) + 8 * (r >> 2) + 4 * h;
                int col = n0 + wn + ni * 32 + m;
                C[(size_t)row * N + col] = acc[mi][ni][r];
            }
}

extern "C" void kernel_launch(void* const* d_in, const int* in_sizes, int n_in,
                              void* d_out, int out_size, void* d_ws, size_t ws_size,
                              hipStream_t stream) {
    const float* x       = (const float*)d_in[0];
    const int*   indices = (const int*)d_in[1];
    const int*   qscales = (const int*)d_in[2];
    float*       out     = (float*)d_out;

    _Float16* W  = (_Float16*)d_ws;                                   // 32 MiB
    _Float16* Xh = (_Float16*)((char*)d_ws + (size_t)TOTAL_W * 2);    // 64 MiB

    k_dequant<<<TOTAL_W / 8 / 256, 256, 0, stream>>>(indices, qscales, W);
    k_cast<<<(size_t)M_TOTAL * IN_F / 8 / 256, 256, 0, stream>>>(x, Xh);

    k_gemm<<<2048, 256, 0, stream>>>(Xh, W, out);
}